// Round 7
// baseline (125.880 us; speedup 1.0000x reference)
//
#include <hip/hip_runtime.h>

#define NNODES 10000
#define NEDGES 4096
#define INF 300
#define OUTF 150
#define EPB 16                      // edges per block
#define NGROUPS (NEDGES / EPB)      // 256
#define SPLITK 15                   // K split over INF
#define KCHUNK (INF / SPLITK)       // 20 (mult of 4: float4-aligned staging, 80B LDS row stride)
#define ETHREADS 192                // lanes 0..149 compute, 150..165 do counts

#define SUMS_N (NNODES * OUTF)

// launch_bounds(192,5): VGPR cap ~102. Live set ~95 (40 burst + 32 acc +
// addressing) -> no spill (R4 lesson) AND 5 waves/SIMD occupancy (R6 lesson:
// 4 waves/SIMD at grid 5/CU left the kernel latency-bound at ~37% occupancy).
__global__ __launch_bounds__(ETHREADS, 5) void edge_msg_kernel(
    const float* __restrict__ feat, const float* __restrict__ efeat,
    const float* __restrict__ W, const float* __restrict__ B,
    const int* __restrict__ src, const int* __restrict__ dst,
    float* __restrict__ sums, float* __restrict__ cnts)
{
    __shared__ float hA[EPB][KCHUNK];   // gathered h chunk (1.28 KB)
    __shared__ float s_ef[EPB];
    __shared__ int   s_dst[EPB];
    __shared__ int   s_src[EPB];

    const int tid = threadIdx.x;
    const int kc  = blockIdx.x / NGROUPS;   // consecutive blocks share kc -> same W rows in L2
    const int grp = blockIdx.x - kc * NGROUPS;
    const int e0  = grp * EPB;
    const int k0  = kc * KCHUNK;

    if (tid < EPB) {
        const int e = e0 + tid;
        s_src[tid] = src[e];
        s_dst[tid] = dst[e];
        s_ef[tid]  = efeat[e];
    }
    __syncthreads();

    // Stage h K-chunk for 16 edges: 16 rows x 5 float4 (all 16B-aligned).
    for (int q = tid; q < EPB * (KCHUNK / 4); q += ETHREADS) {
        const int el = q / (KCHUNK / 4);
        const int j4 = q - el * (KCHUNK / 4);
        *(float4*)&hA[el][4 * j4] =
            *(const float4*)(feat + (size_t)s_src[el] * INF + k0 + 4 * j4);
    }
    __syncthreads();

    if (tid < OUTF) {
        float accW[EPB], accB[EPB];     // dual acc: each h elem feeds 2 FMAs
        #pragma unroll
        for (int e = 0; e < EPB; ++e) { accW[e] = 0.f; accB[e] = 0.f; }

        const float* Wc = W + (size_t)k0 * OUTF + tid;  // column o = tid
        const float* Bc = B + (size_t)k0 * OUTF + tid;

        // Single burst: all 40 W/B scalars issued as independent coalesced
        // L2 loads (one latency exposure), statically indexed -> registers.
        float wr[KCHUNK], br[KCHUNK];
        #pragma unroll
        for (int r = 0; r < KCHUNK; ++r) {
            wr[r] = Wc[(size_t)r * OUTF];
            br[r] = Bc[(size_t)r * OUTF];
        }
        #pragma unroll
        for (int i4 = 0; i4 < KCHUNK; i4 += 4) {
            #pragma unroll
            for (int e = 0; e < EPB; ++e) {
                const float4 h = *(const float4*)&hA[e][i4];  // broadcast, conflict-free
                accW[e] = fmaf(h.w, wr[i4 + 3], fmaf(h.z, wr[i4 + 2],
                          fmaf(h.y, wr[i4 + 1], fmaf(h.x, wr[i4 + 0], accW[e]))));
                accB[e] = fmaf(h.w, br[i4 + 3], fmaf(h.z, br[i4 + 2],
                          fmaf(h.y, br[i4 + 1], fmaf(h.x, br[i4 + 0], accB[e]))));
            }
        }
        // partial msg for this K-chunk (linear in K -> split-K atomics OK)
        #pragma unroll
        for (int e = 0; e < EPB; ++e) {
            const float msg = fmaf(s_ef[e], accW[e], accB[e]);
            atomicAdd(&sums[(size_t)s_dst[e] * OUTF + tid], msg);
        }
    } else if (kc == 0 && tid < OUTF + EPB) {
        atomicAdd(&cnts[s_dst[tid - OUTF]], 1.0f);   // each edge counted once
    }
}

__global__ __launch_bounds__(256) void finalize_kernel(
    const float* __restrict__ sums, const float* __restrict__ cnts,
    const float* __restrict__ bias, float* __restrict__ out)
{
    const int idx = blockIdx.x * blockDim.x + threadIdx.x;
    if (idx < SUMS_N) {
        const int n = idx / OUTF;
        const int o = idx - n * OUTF;
        const float c = cnts[n];
        const float m = sums[idx] / fmaxf(c, 1.0f);
        const float v = m + bias[o];
        out[idx] = v > 0.f ? v : 0.f;
    }
}

extern "C" void kernel_launch(void* const* d_in, const int* in_sizes, int n_in,
                              void* d_out, int out_size, void* d_ws, size_t ws_size,
                              hipStream_t stream) {
    const float* feat  = (const float*)d_in[0];
    const float* efeat = (const float*)d_in[1];
    const float* W     = (const float*)d_in[2];
    const float* B     = (const float*)d_in[3];
    const float* bias  = (const float*)d_in[4];
    const int*   src   = (const int*)d_in[5];
    const int*   dst   = (const int*)d_in[6];
    float* out  = (float*)d_out;

    float* sums = (float*)d_ws;                 // [NNODES*OUTF]
    float* cnts = sums + SUMS_N;                // [NNODES]

    hipMemsetAsync(d_ws, 0, (size_t)(SUMS_N + NNODES) * sizeof(float), stream);

    edge_msg_kernel<<<NGROUPS * SPLITK, ETHREADS, 0, stream>>>(
        feat, efeat, W, B, src, dst, sums, cnts);

    finalize_kernel<<<(SUMS_N + 255) / 256, 256, 0, stream>>>(sums, cnts, bias, out);
}

// Round 8
// 101.344 us; speedup vs baseline: 1.2421x; 1.2421x over previous
//
#include <hip/hip_runtime.h>

#define NNODES 10000
#define NEDGES 4096
#define INF 300
#define OUTF 150
#define EPB 16                      // edges per block
#define NGROUPS (NEDGES / EPB)      // 256
#define SPLITK 5                    // K split over INF; 300/5 = 60
#define KCHUNK (INF / SPLITK)       // 60
#define PHASES 3                    // burst phases of 20 rows
#define PROWS (KCHUNK / PHASES)     // 20 -> 40 burst regs live per phase
#define ETHREADS 192                // lanes 0..149 compute

#define SUMS_N (NNODES * OUTF)      // 1,500,000
#define MSGS_N (NEDGES * OUTF)      //   614,400

// launch_bounds(192,4): 128-VGPR cap; live ~92 regs -> no spill (R4 lesson),
// headroom so the burst actually stays in registers (R7: cap-5 gave VGPR=40
// because the scheduler shredded the burst to shrink live ranges).
__global__ __launch_bounds__(ETHREADS, 4) void edge_msg_kernel(
    const float* __restrict__ feat, const float* __restrict__ efeat,
    const float* __restrict__ W, const float* __restrict__ B,
    const int* __restrict__ src,
    float* __restrict__ part)
{
    __shared__ float hA[EPB][KCHUNK];   // gathered h chunk (3.84 KB)
    __shared__ float s_ef[EPB];
    __shared__ int   s_src[EPB];

    const int tid = threadIdx.x;
    const int kc  = blockIdx.x / NGROUPS;   // consecutive blocks share kc -> W rows L2-hot
    const int grp = blockIdx.x - kc * NGROUPS;
    const int e0  = grp * EPB;
    const int k0  = kc * KCHUNK;

    if (tid < EPB) {
        const int e = e0 + tid;
        s_src[tid] = src[e];
        s_ef[tid]  = efeat[e];
    }
    __syncthreads();

    // Stage h K-chunk for 16 edges: 16 rows x 15 float4 (16B-aligned).
    for (int q = tid; q < EPB * (KCHUNK / 4); q += ETHREADS) {
        const int el = q / (KCHUNK / 4);
        const int j4 = q - el * (KCHUNK / 4);
        *(float4*)&hA[el][4 * j4] =
            *(const float4*)(feat + (size_t)s_src[el] * INF + k0 + 4 * j4);
    }
    __syncthreads();

    if (tid < OUTF) {
        float accW[EPB], accB[EPB];     // dual acc: each h elem feeds 2 FMAs
        #pragma unroll
        for (int e = 0; e < EPB; ++e) { accW[e] = 0.f; accB[e] = 0.f; }

        const float* Wc = W + (size_t)k0 * OUTF + tid;  // column o = tid
        const float* Bc = B + (size_t)k0 * OUTF + tid;

        #pragma unroll
        for (int ph = 0; ph < PHASES; ++ph) {
            const int base = ph * PROWS;
            float wr[PROWS], br[PROWS];
            #pragma unroll
            for (int r = 0; r < PROWS; ++r) {
                wr[r] = Wc[(size_t)(base + r) * OUTF];   // 40 independent coalesced L2 loads
                br[r] = Bc[(size_t)(base + r) * OUTF];
            }
            // Pin: no FMA may hoist above this point -> the 40 loads issue as
            // one back-to-back burst (single latency exposure). Next phase's
            // burst lives in the SAME region as this phase's FMAs and can be
            // issued early by the scheduler (free pipelining, no dbuf regs).
            __builtin_amdgcn_sched_barrier(0);
            #pragma unroll
            for (int i4 = 0; i4 < PROWS; i4 += 4) {
                #pragma unroll
                for (int e = 0; e < EPB; ++e) {
                    const float4 h = *(const float4*)&hA[e][base + i4]; // broadcast, conflict-free
                    accW[e] = fmaf(h.w, wr[i4 + 3], fmaf(h.z, wr[i4 + 2],
                              fmaf(h.y, wr[i4 + 1], fmaf(h.x, wr[i4 + 0], accW[e]))));
                    accB[e] = fmaf(h.w, br[i4 + 3], fmaf(h.z, br[i4 + 2],
                              fmaf(h.y, br[i4 + 1], fmaf(h.x, br[i4 + 0], accB[e]))));
                }
            }
        }
        // Dense partial store (coalesced, NO atomic RMW): part[kc][e][o]
        float* pp = part + (size_t)kc * MSGS_N + (size_t)e0 * OUTF + tid;
        #pragma unroll
        for (int e = 0; e < EPB; ++e)
            pp[(size_t)e * OUTF] = fmaf(s_ef[e], accW[e], accB[e]);
    }
}

// Sum SPLITK partials per (e,o); ONE atomic per (e,o) into sums; counts here too.
__global__ __launch_bounds__(256) void reduce_scatter_kernel(
    const float* __restrict__ part, const int* __restrict__ dst,
    float* __restrict__ sums, float* __restrict__ cnts)
{
    const int idx = blockIdx.x * blockDim.x + threadIdx.x;
    if (idx < MSGS_N) {
        const int e = idx / OUTF;
        const int o = idx - e * OUTF;
        float s = 0.f;
        #pragma unroll
        for (int kc = 0; kc < SPLITK; ++kc)
            s += part[(size_t)kc * MSGS_N + idx];      // coalesced reads
        const int d = dst[e];
        atomicAdd(&sums[(size_t)d * OUTF + o], s);
        if (o == 0) atomicAdd(&cnts[d], 1.0f);         // each edge counted once
    }
}

__global__ __launch_bounds__(256) void finalize_kernel(
    const float* __restrict__ sums, const float* __restrict__ cnts,
    const float* __restrict__ bias, float* __restrict__ out)
{
    const int idx = blockIdx.x * blockDim.x + threadIdx.x;
    if (idx < SUMS_N) {
        const int n = idx / OUTF;
        const int o = idx - n * OUTF;
        const float c = cnts[n];
        const float m = sums[idx] / fmaxf(c, 1.0f);
        const float v = m + bias[o];
        out[idx] = v > 0.f ? v : 0.f;
    }
}

extern "C" void kernel_launch(void* const* d_in, const int* in_sizes, int n_in,
                              void* d_out, int out_size, void* d_ws, size_t ws_size,
                              hipStream_t stream) {
    const float* feat  = (const float*)d_in[0];
    const float* efeat = (const float*)d_in[1];
    const float* W     = (const float*)d_in[2];
    const float* B     = (const float*)d_in[3];
    const float* bias  = (const float*)d_in[4];
    const int*   src   = (const int*)d_in[5];
    const int*   dst   = (const int*)d_in[6];
    float* out  = (float*)d_out;

    float* sums = (float*)d_ws;                         // [SUMS_N]
    float* cnts = sums + SUMS_N;                        // [NNODES]
    float* part = cnts + NNODES;                        // [SPLITK * MSGS_N]

    // zero only sums+cnts (part is fully overwritten by edge_msg_kernel)
    hipMemsetAsync(d_ws, 0, (size_t)(SUMS_N + NNODES) * sizeof(float), stream);

    edge_msg_kernel<<<NGROUPS * SPLITK, ETHREADS, 0, stream>>>(
        feat, efeat, W, B, src, part);

    reduce_scatter_kernel<<<(MSGS_N + 255) / 256, 256, 0, stream>>>(
        part, dst, sums, cnts);

    finalize_kernel<<<(SUMS_N + 255) / 256, 256, 0, stream>>>(sums, cnts, bias, out);
}